// Round 10
// baseline (165.684 us; speedup 1.0000x reference)
//
#include <hip/hip_runtime.h>
#include <math.h>

// Retention via chunked linear attention — round-9 pipeline + PROBE kernels.
// Pipeline (verified, 59.0us) is unchanged and produces the output.
// probe_{proj,mid,out} re-run the fat kernel bodies 8x into scratch so each
// surfaces in rocprof top-5 with its own counters (bodies alone are <40us and
// invisible under the harness poison-fills).

constexpr int B = 8, S = 2048, D = 128;
constexpr int C = 64, NC = S / C;
constexpr int BS = B * S;
constexpr int NCH = B * NC;            // 256 chunks
constexpr int PROBE_REPS = 8;
#define GAMMA_F 0.9865f

typedef __attribute__((ext_vector_type(8))) short short8;
typedef __attribute__((ext_vector_type(8))) unsigned short ushort8;
typedef __attribute__((ext_vector_type(4))) float f32x4;

__device__ inline unsigned short f2bf(float f) {
  unsigned u = __builtin_bit_cast(unsigned, f);
  return (unsigned short)((u + 0x7FFF + ((u >> 16) & 1)) >> 16);   // RNE
}
__device__ inline float bf2f(unsigned short h) {
  return __builtin_bit_cast(float, (unsigned)h << 16);
}

// ---------------- K0: wt = W^T bf16 + decay scalars ----------------
__global__ void k_init(const float* __restrict__ W, unsigned short* __restrict__ wt,
                       float* __restrict__ qs, float* __restrict__ ks) {
  int bid = blockIdx.x, tid = threadIdx.x;
  if (bid < 64) {
    int idx = bid * 256 + tid;
    int k = idx & 127, c = idx >> 7;
    wt[c * 128 + k] = f2bf(W[k * 128 + c]);
  } else {
    int n = (bid - 64) * 256 + tid;
    if (n < S) {
      double g = (double)GAMMA_F;
      double lg = log(g);
      double gmn = exp(-lg * (double)n);
      double gn  = exp(lg * (double)n);
      double ginv = 1.0 / g;
      double rs = (exp(log(ginv) * (double)(n + 1)) - 1.0) / (ginv - 1.0);
      qs[n] = (float)(gmn / sqrt(128.0));
      ks[n] = (float)(gn / sqrt(rs));
    }
  }
}

// ---------------- proj body ----------------
__device__ __forceinline__ void proj_body(
    int mat, int bc, int tid, const float* __restrict__ X,
    const unsigned short* __restrict__ wt,
    const float* __restrict__ qs, const float* __restrict__ ks,
    unsigned short* __restrict__ Ob, float* __restrict__ cs,
    float (*css)[128]) {
  int w = tid >> 6, lane = tid & 63;
  int r0 = bc * 64 + w * 16;
  int arow = r0 + (lane & 15);
  int kg = (lane >> 4) * 8;

  f32x4 acc[8];
#pragma unroll
  for (int j = 0; j < 8; j++) acc[j] = (f32x4){0.f, 0.f, 0.f, 0.f};
#pragma unroll
  for (int t = 0; t < 4; t++) {
    int k0 = t * 32 + kg;
    const float* ap = X + (size_t)arow * 128 + k0;
    float a8[8];
    *(f32x4*)(a8) = *(const f32x4*)ap;
    *(f32x4*)(a8 + 4) = *(const f32x4*)(ap + 4);
    short8 af;
#pragma unroll
    for (int i = 0; i < 8; i++) af[i] = (short)f2bf(a8[i]);
#pragma unroll
    for (int j = 0; j < 8; j++) {
      short8 bf = *(const short8*)(wt + (size_t)(j * 16 + (lane & 15)) * 128 + k0);
      acc[j] = __builtin_amdgcn_mfma_f32_16x16x32_bf16(af, bf, acc[j], 0, 0, 0);
    }
  }
  int crow = r0 + (lane >> 4) * 4;
  float csp[8];
#pragma unroll
  for (int j = 0; j < 8; j++) csp[j] = 0.f;
#pragma unroll
  for (int rr = 0; rr < 4; rr++) {
    int row = crow + rr;
    int n = row & (S - 1);
    float sc = (mat == 0) ? qs[n] : ((mat == 1) ? ks[n] : 1.0f);
#pragma unroll
    for (int j = 0; j < 8; j++) {
      float v = acc[j][rr] * sc;
      Ob[(size_t)row * 128 + j * 16 + (lane & 15)] = f2bf(v);
      csp[j] += v;
    }
  }
  if (mat == 1) {
#pragma unroll
    for (int j = 0; j < 8; j++) {
      csp[j] += __shfl_xor(csp[j], 16);
      csp[j] += __shfl_xor(csp[j], 32);
    }
    if ((lane >> 4) == 0)
#pragma unroll
      for (int j = 0; j < 8; j++) css[w][j * 16 + lane] = csp[j];
  }
  __syncthreads();
  if (mat == 1 && tid < 128)
    cs[bc * 128 + tid] = css[0][tid] + css[1][tid] + css[2][tid] + css[3][tid];
}

__global__ __launch_bounds__(256) void k_proj(
    const float* __restrict__ xq, const float* __restrict__ xk,
    const float* __restrict__ xv, const unsigned short* __restrict__ wt,
    const float* __restrict__ qs, const float* __restrict__ ks,
    unsigned short* __restrict__ qb, unsigned short* __restrict__ kb,
    unsigned short* __restrict__ vb, float* __restrict__ cs) {
  __shared__ float css[4][128];
  int mat = blockIdx.y;
  const float* X = (mat == 0) ? xq : ((mat == 1) ? xk : xv);
  unsigned short* Ob = (mat == 0) ? qb : ((mat == 1) ? kb : vb);
  proj_body(mat, blockIdx.x, threadIdx.x, X, wt, qs, ks, Ob, cs, css);
}

__global__ __launch_bounds__(256) void probe_proj(
    const float* __restrict__ xq, const float* __restrict__ xk,
    const float* __restrict__ xv, const unsigned short* __restrict__ wt,
    const float* __restrict__ qs, const float* __restrict__ ks,
    unsigned short* __restrict__ qb2, unsigned short* __restrict__ kb2,
    unsigned short* __restrict__ vb2, float* __restrict__ cs2) {
  __shared__ float css[4][128];
  int mat = blockIdx.y;
  const float* X = (mat == 0) ? xq : ((mat == 1) ? xk : xv);
  unsigned short* Ob = (mat == 0) ? qb2 : ((mat == 1) ? kb2 : vb2);
  for (int r = 0; r < PROBE_REPS; r++) {
    proj_body(mat, blockIdx.x, threadIdx.x, X, wt, qs, ks, Ob, cs2, css);
    __syncthreads();
  }
}

// ---------------- mid body (512 threads) ----------------
__device__ __forceinline__ void mid_body(
    int bc, int tid,
    const unsigned short* __restrict__ qb, const unsigned short* __restrict__ kb,
    const unsigned short* __restrict__ vb, const float* __restrict__ cs,
    unsigned short* __restrict__ al, unsigned short* __restrict__ vbT,
    unsigned short* __restrict__ Hc,
    unsigned short (*kraw)[136], unsigned short (*kT)[72], unsigned short (*vT)[72],
    float* csp, float* invl, float (*rsum_l)[64]) {
  int b = bc >> 5, c = bc & 31;
  int w = tid >> 6, lane = tid & 63;
  int l15 = lane & 15;
  int kg = (lane >> 4) * 8;
  size_t base = (size_t)bc * C * D;

  if (tid < 128) {
    float a = 0.f;
    for (int cc = 0; cc < c; cc++) a += cs[(size_t)(b * NC + cc) * 128 + tid];
    csp[tid] = a;
  }
  // Phase A: A = tril(Q'K''^T)
  {
    int rt = w & 3, mh = w >> 2;
    int arow = rt * 16 + l15;
    int crow = rt * 16 + (lane >> 4) * 4;
    f32x4 a1[2];
#pragma unroll
    for (int mi = 0; mi < 2; mi++) a1[mi] = (f32x4){0.f, 0.f, 0.f, 0.f};
#pragma unroll
    for (int t = 0; t < 4; t++) {
      int k0 = t * 32 + kg;
      short8 af = *(const short8*)(qb + base + (size_t)arow * D + k0);
#pragma unroll
      for (int mi = 0; mi < 2; mi++) {
        int mt = mh * 2 + mi;
        short8 bf = *(const short8*)(kb + base + (size_t)(mt * 16 + l15) * D + k0);
        a1[mi] = __builtin_amdgcn_mfma_f32_16x16x32_bf16(af, bf, a1[mi], 0, 0, 0);
      }
    }
    unsigned short* alg = al + (size_t)bc * 64 * 64;
    float rsp[4] = {0.f, 0.f, 0.f, 0.f};
#pragma unroll
    for (int mi = 0; mi < 2; mi++)
#pragma unroll
      for (int rr = 0; rr < 4; rr++) {
        int n_l = crow + rr, m_l = (mh * 2 + mi) * 16 + l15;
        float mv = (n_l >= m_l) ? a1[mi][rr] : 0.f;
        alg[n_l * 64 + m_l] = f2bf(mv);
        rsp[rr] += mv;
      }
#pragma unroll
    for (int rr = 0; rr < 4; rr++) {
      float r = rsp[rr];
      r += __shfl_xor(r, 1); r += __shfl_xor(r, 2);
      r += __shfl_xor(r, 4); r += __shfl_xor(r, 8);
      if (l15 == 0) rsum_l[mh][crow + rr] = r;
    }
  }
  // Phase C: stage K chunk
#pragma unroll
  for (int i = 0; i < 2; i++) {
    int e = (i * 512 + tid) * 8;
    *(ushort8*)&kraw[e >> 7][e & 127] = *(const ushort8*)(kb + base + e);
  }
  __syncthreads();

  // Phase B: s and invl
  {
    int row = tid >> 3, part = tid & 7;
    const unsigned short* q = qb + base + (size_t)row * D + part * 16;
    ushort8 q8a = *(const ushort8*)q;
    ushort8 q8b = *(const ushort8*)(q + 8);
    float dot = 0.f;
#pragma unroll
    for (int ii = 0; ii < 8; ii++) {
      dot = fmaf(bf2f(q8a[ii]), csp[part * 16 + ii], dot);
      dot = fmaf(bf2f(q8b[ii]), csp[part * 16 + 8 + ii], dot);
    }
    dot += __shfl_xor(dot, 1); dot += __shfl_xor(dot, 2); dot += __shfl_xor(dot, 4);
    if (part == 0) {
      float s = rsum_l[0][row] + rsum_l[1][row] + dot;
      invl[row] = 1.f / fmaxf(fabsf(s), 1.f);
    }
  }
  // Phase D: kT pack
  {
    int d = tid & 127, mh2 = tid >> 7;
#pragma unroll
    for (int mg = 0; mg < 2; mg++) {
      ushort8 pk;
#pragma unroll
      for (int i = 0; i < 8; i++) pk[i] = kraw[mh2 * 16 + mg * 8 + i][d];
      *(ushort8*)&kT[d][mh2 * 16 + mg * 8] = pk;
    }
  }
  __syncthreads();
  // Phase E: V' = V * invl -> kraw
#pragma unroll
  for (int i = 0; i < 2; i++) {
    int e = (i * 512 + tid) * 8;
    int row = e >> 7, col = e & 127;
    ushort8 v8 = *(const ushort8*)(vb + base + e);
    float inv = invl[row];
    ushort8 o;
#pragma unroll
    for (int ii = 0; ii < 8; ii++) o[ii] = f2bf(bf2f(v8[ii]) * inv);
    *(ushort8*)&kraw[row][col] = o;
  }
  __syncthreads();
  // Phase F: vT pack
  {
    int d = tid & 127, mh2 = tid >> 7;
#pragma unroll
    for (int mg = 0; mg < 2; mg++) {
      ushort8 pk;
#pragma unroll
      for (int i = 0; i < 8; i++) pk[i] = kraw[mh2 * 16 + mg * 8 + i][d];
      *(ushort8*)&vT[d][mh2 * 16 + mg * 8] = pk;
    }
  }
  __syncthreads();
  // Phase G: Hc
  {
    f32x4 hacc[8];
#pragma unroll
    for (int j = 0; j < 8; j++) hacc[j] = (f32x4){0.f, 0.f, 0.f, 0.f};
#pragma unroll
    for (int t = 0; t < 2; t++) {
      int k0 = t * 32 + kg;
      short8 a2 = *(const short8*)&vT[w * 16 + l15][k0];
#pragma unroll
      for (int j = 0; j < 8; j++) {
        short8 bf = *(const short8*)&kT[j * 16 + l15][k0];
        hacc[j] = __builtin_amdgcn_mfma_f32_16x16x32_bf16(a2, bf, hacc[j], 0, 0, 0);
      }
    }
    unsigned short* g = Hc + (size_t)bc * D * D;
#pragma unroll
    for (int j = 0; j < 8; j++)
#pragma unroll
      for (int rr = 0; rr < 4; rr++)
        g[(size_t)(w * 16 + (lane >> 4) * 4 + rr) * D + j * 16 + l15] =
            f2bf(hacc[j][rr]);
  }
  // vbT -> global
  {
    int d = tid >> 2, pp = (tid & 3) * 16;
    unsigned short* dst = vbT + (size_t)bc * D * C + (size_t)d * C + pp;
    *(ushort8*)(dst) = *(ushort8*)&vT[d][pp];
    *(ushort8*)(dst + 8) = *(ushort8*)&vT[d][pp + 8];
  }
}

__global__ __launch_bounds__(512) void k_mid(
    const unsigned short* __restrict__ qb, const unsigned short* __restrict__ kb,
    const unsigned short* __restrict__ vb, const float* __restrict__ cs,
    unsigned short* __restrict__ al, unsigned short* __restrict__ vbT,
    unsigned short* __restrict__ Hc) {
  __shared__ unsigned short kraw[64][136];
  __shared__ unsigned short kT[128][72];
  __shared__ unsigned short vT[128][72];
  __shared__ float csp[128];
  __shared__ float invl[64];
  __shared__ float rsum_l[2][64];
  mid_body(blockIdx.x, threadIdx.x, qb, kb, vb, cs, al, vbT, Hc,
           kraw, kT, vT, csp, invl, rsum_l);
}

__global__ __launch_bounds__(512) void probe_mid(
    const unsigned short* __restrict__ qb, const unsigned short* __restrict__ kb,
    const unsigned short* __restrict__ vb, const float* __restrict__ cs,
    unsigned short* __restrict__ al2, unsigned short* __restrict__ vbT2,
    unsigned short* __restrict__ Hc2) {
  __shared__ unsigned short kraw[64][136];
  __shared__ unsigned short kT[128][72];
  __shared__ unsigned short vT[128][72];
  __shared__ float csp[128];
  __shared__ float invl[64];
  __shared__ float rsum_l[2][64];
  for (int r = 0; r < PROBE_REPS; r++) {
    mid_body(blockIdx.x, threadIdx.x, qb, kb, vb, cs, al2, vbT2, Hc2,
             kraw, kT, vT, csp, invl, rsum_l);
    __syncthreads();
  }
}

// ---------------- K3: HS = exclusive chunk prefix of Hc ----------------
__global__ __launch_bounds__(64) void k_gscan(const unsigned short* __restrict__ Hc,
                                              unsigned short* __restrict__ HS) {
  int b = blockIdx.x, gy = blockIdx.y, t = threadIdx.x;
  int d2 = gy * 4 + (t >> 4), d1 = (t & 15) * 8;
  size_t off = ((size_t)(b * NC) * D + d2) * D + d1;
  ushort8 v[NC];
#pragma unroll
  for (int c = 0; c < NC; c++)
    v[c] = *(const ushort8*)(Hc + off + (size_t)c * D * D);
  float run[8];
#pragma unroll
  for (int j = 0; j < 8; j++) run[j] = 0.f;
#pragma unroll
  for (int c = 0; c < NC; c++) {
    ushort8 o;
#pragma unroll
    for (int j = 0; j < 8; j++) {
      o[j] = f2bf(run[j]);
      run[j] += bf2f(v[c][j]);
    }
    *(ushort8*)(HS + off + (size_t)c * D * D) = o;
  }
}

// ---------------- out body (512 threads, no LDS) ----------------
__device__ __forceinline__ void out_body(
    int bc, int tid,
    const unsigned short* __restrict__ qb, const unsigned short* __restrict__ al,
    const unsigned short* __restrict__ vbT, const unsigned short* __restrict__ HS,
    float* __restrict__ out) {
  int w = tid >> 6, lane = tid & 63;
  int l15 = lane & 15;
  size_t base = (size_t)bc * C * D;
  int kg = (lane >> 4) * 8;
  int rt = w >> 1, ch = w & 1;
  int arow = rt * 16 + l15;
  int crow = rt * 16 + (lane >> 4) * 4;

  f32x4 acc[4];
#pragma unroll
  for (int j = 0; j < 4; j++) acc[j] = (f32x4){0.f, 0.f, 0.f, 0.f};
  const unsigned short* hrow = HS + (size_t)bc * D * D;
#pragma unroll
  for (int t = 0; t < 4; t++) {
    int k0 = t * 32 + kg;
    short8 af = *(const short8*)(qb + base + (size_t)arow * D + k0);
#pragma unroll
    for (int jj = 0; jj < 4; jj++) {
      int j = ch * 4 + jj;
      short8 bf = *(const short8*)(hrow + (size_t)(j * 16 + l15) * D + k0);
      acc[jj] = __builtin_amdgcn_mfma_f32_16x16x32_bf16(af, bf, acc[jj], 0, 0, 0);
    }
  }
  const unsigned short* alg = al + (size_t)bc * 64 * 64;
  const unsigned short* vt = vbT + (size_t)bc * D * C;
#pragma unroll
  for (int t = 0; t < 2; t++) {
    int k0 = t * 32 + kg;
    short8 af = *(const short8*)(alg + (size_t)arow * 64 + k0);
#pragma unroll
    for (int jj = 0; jj < 4; jj++) {
      int j = ch * 4 + jj;
      short8 bf = *(const short8*)(vt + (size_t)(j * 16 + l15) * C + k0);
      acc[jj] = __builtin_amdgcn_mfma_f32_16x16x32_bf16(af, bf, acc[jj], 0, 0, 0);
    }
  }
#pragma unroll
  for (int jj = 0; jj < 4; jj++)
#pragma unroll
    for (int rr = 0; rr < 4; rr++)
      out[base + (size_t)(crow + rr) * D + (ch * 4 + jj) * 16 + l15] = acc[jj][rr];
}

__global__ __launch_bounds__(512) void k_out(
    const unsigned short* __restrict__ qb, const unsigned short* __restrict__ al,
    const unsigned short* __restrict__ vbT, const unsigned short* __restrict__ HS,
    float* __restrict__ out) {
  out_body(blockIdx.x, threadIdx.x, qb, al, vbT, HS, out);
}

__global__ __launch_bounds__(512) void probe_out(
    const unsigned short* __restrict__ qb, const unsigned short* __restrict__ al,
    const unsigned short* __restrict__ vbT, const unsigned short* __restrict__ HS,
    float* __restrict__ out2) {
  for (int r = 0; r < PROBE_REPS; r++)
    out_body(blockIdx.x, threadIdx.x, qb, al, vbT, HS, out2);
}

extern "C" void kernel_launch(void* const* d_in, const int* in_sizes, int n_in,
                              void* d_out, int out_size, void* d_ws, size_t ws_size,
                              hipStream_t stream) {
  const float* xq = (const float*)d_in[0];
  const float* xk = (const float*)d_in[1];
  const float* xv = (const float*)d_in[2];
  const float* W  = (const float*)d_in[3];
  float* out = (float*)d_out;

  char* p = (char*)d_ws;
  unsigned short* qb  = (unsigned short*)p;  p += (size_t)BS * D * 2;
  unsigned short* kb  = (unsigned short*)p;  p += (size_t)BS * D * 2;
  unsigned short* vb  = (unsigned short*)p;  p += (size_t)BS * D * 2;
  unsigned short* vbT = (unsigned short*)p;  p += (size_t)NCH * D * C * 2;
  unsigned short* al  = (unsigned short*)p;  p += (size_t)NCH * C * C * 2;
  unsigned short* Hc  = (unsigned short*)p;  p += (size_t)NCH * D * D * 2;
  unsigned short* HS  = (unsigned short*)p;  p += (size_t)NCH * D * D * 2;
  unsigned short* wt  = (unsigned short*)p;  p += (size_t)D * D * 2;
  float* cs = (float*)p;                     p += (size_t)NCH * D * 4;
  float* qs = (float*)p;                     p += (size_t)S * 4;
  float* ks = (float*)p;                     p += (size_t)S * 4;
  // probe scratch (disjoint)
  unsigned short* qb2  = (unsigned short*)p; p += (size_t)BS * D * 2;
  unsigned short* kb2  = (unsigned short*)p; p += (size_t)BS * D * 2;
  unsigned short* vb2  = (unsigned short*)p; p += (size_t)BS * D * 2;
  unsigned short* vbT2 = (unsigned short*)p; p += (size_t)NCH * D * C * 2;
  unsigned short* al2  = (unsigned short*)p; p += (size_t)NCH * C * C * 2;
  unsigned short* Hc2  = (unsigned short*)p; p += (size_t)NCH * D * D * 2;
  float* cs2 = (float*)p;                    p += (size_t)NCH * D * 4;
  float* out2 = (float*)p;                   p += (size_t)BS * D * 4;

  // real pipeline (output correctness)
  hipLaunchKernelGGL(k_init, dim3(72), dim3(256), 0, stream, W, wt, qs, ks);
  hipLaunchKernelGGL(k_proj, dim3(NCH, 3), dim3(256), 0, stream,
                     xq, xk, xv, wt, qs, ks, qb, kb, vb, cs);
  hipLaunchKernelGGL(k_mid, dim3(NCH), dim3(512), 0, stream, qb, kb, vb, cs,
                     al, vbT, Hc);
  hipLaunchKernelGGL(k_gscan, dim3(B, 32), dim3(64), 0, stream, Hc, HS);
  hipLaunchKernelGGL(k_out, dim3(NCH), dim3(512), 0, stream, qb, al, vbT, HS, out);
  // probes (measurement only; write scratch)
  hipLaunchKernelGGL(probe_proj, dim3(NCH, 3), dim3(256), 0, stream,
                     xq, xk, xv, wt, qs, ks, qb2, kb2, vb2, cs2);
  hipLaunchKernelGGL(probe_mid, dim3(NCH), dim3(512), 0, stream, qb, kb, vb, cs,
                     al2, vbT2, Hc2);
  hipLaunchKernelGGL(probe_out, dim3(NCH), dim3(512), 0, stream, qb, al, vbT, HS, out2);
}

// Round 11
// 51.551 us; speedup vs baseline: 3.2140x; 3.2140x over previous
//
#include <hip/hip_runtime.h>
#include <math.h>

// Retention via chunked linear attention — 4-kernel fused pipeline.
//   k_y:    yc[b,c][k] = sum_{m in chunk c} ks[m]*xk[b,m][k]   (raw-space prefix feed)
//   k_big:  per chunk: W^T in LDS; Q',K'',V = (x@W)*scale in LDS; csp = (prefix yc)@W;
//           A = tril(Q'K''^T) -> al; s = rowsum(A)+Q'.csp; V' = V/max(|s|,1);
//           kT/vT packs; Hc = (K''^T V')^T -> global; qb, vbT -> global
//   k_gscan: HS = exclusive chunk prefix of Hc (f32 accum, bf16 out)
//   k_out:  out = Q'@SE + A@V'
// csp identity: sum_{m<64c} K''[m] = (sum_{m<64c} ks[m]*xk[m]) @ W  (exact).

constexpr int B = 8, S = 2048, D = 128;
constexpr int C = 64, NC = S / C;
constexpr int BS = B * S;
constexpr int NCH = B * NC;            // 256 chunks
#define GAMMA_F 0.9865f

typedef __attribute__((ext_vector_type(8))) short short8;
typedef __attribute__((ext_vector_type(8))) unsigned short ushort8;
typedef __attribute__((ext_vector_type(4))) float f32x4;

__device__ inline unsigned short f2bf(float f) {
  unsigned u = __builtin_bit_cast(unsigned, f);
  return (unsigned short)((u + 0x7FFF + ((u >> 16) & 1)) >> 16);   // RNE
}
__device__ inline float bf2f(unsigned short h) {
  return __builtin_bit_cast(float, (unsigned)h << 16);
}

// ---------------- K0: per-chunk ks-weighted xk column sums ----------------
__global__ __launch_bounds__(128) void k_y(const float* __restrict__ xk,
                                           float* __restrict__ yc) {
  __shared__ float ksl[64];
  int bc = blockIdx.x, tid = threadIdx.x;
  float lgf = logf(GAMMA_F);
  if (tid < 64) {
    int n = (bc * 64 + tid) & (S - 1);
    float rs = (expf(-lgf * (float)(n + 1)) - 1.f) * (GAMMA_F / (1.f - GAMMA_F));
    ksl[tid] = expf(lgf * (float)n) / sqrtf(rs);     // gamma^n / sqrt(rowsum)
  }
  __syncthreads();
  const float* x = xk + (size_t)bc * 64 * 128 + tid;
  float a = 0.f;
#pragma unroll
  for (int j = 0; j < 64; j++) a = fmaf(ksl[j], x[j * 128], a);
  yc[(size_t)bc * 128 + tid] = a;
}

// ---------------- K1: fused proj + mid (512 threads, ~91 KB LDS) ----------------
__global__ __launch_bounds__(512) void k_big(
    const float* __restrict__ xq, const float* __restrict__ xk,
    const float* __restrict__ xv, const float* __restrict__ W,
    const float* __restrict__ yc, unsigned short* __restrict__ qb,
    unsigned short* __restrict__ al, unsigned short* __restrict__ vbT,
    unsigned short* __restrict__ Hc) {
  __shared__ unsigned short qkv[3][64][136];       // 52.2 KB  Q',K'',V(->V' via vT)
  __shared__ alignas(16) char ovl[36864];          // 36.9 KB  wt then kT+vT
  __shared__ float csp[128];
  __shared__ float ysum[128];
  __shared__ float cspp[4][128];
  __shared__ float invl[64];
  __shared__ float rsum_l[2][64];
  auto wt = (unsigned short(*)[136])ovl;           // P0..P1 only
  auto kT = (unsigned short(*)[72])ovl;            // P2 onward
  auto vT = (unsigned short(*)[72])(ovl + 18432);  // P2 onward

  int bc = blockIdx.x, b = bc >> 5, c = bc & 31;
  int tid = threadIdx.x, w = tid >> 6, lane = tid & 63;
  int l15 = lane & 15, kg = (lane >> 4) * 8;
  float lgf = logf(GAMMA_F);

  // ---- P0: wt = W^T (bf16, LDS) ; ysum = prefix of yc over prior chunks ----
  for (int idx = tid; idx < 128 * 128; idx += 512) {
    int cc = idx >> 7, k = idx & 127;      // conflict-free LDS writes; W L2-resident
    wt[cc][k] = f2bf(W[k * 128 + cc]);
  }
  if (tid < 128) {
    float a = 0.f;
    for (int cc = 0; cc < c; cc++) a += yc[(size_t)(b * NC + cc) * 128 + tid];
    ysum[tid] = a;
  }
  __syncthreads();

  // ---- P1: projections into LDS. Wave w: rows rt=w&3, col-half chh=w>>2 ----
  int rt = w & 3, chh = w >> 2;
  {
    int arow = rt * 16 + l15;
    size_t grow = (size_t)(bc * 64 + arow) * 128;
    for (int mat = 0; mat < 3; mat++) {
      const float* X = (mat == 0) ? xq : ((mat == 1) ? xk : xv);
      f32x4 acc[4];
#pragma unroll
      for (int j = 0; j < 4; j++) acc[j] = (f32x4){0.f, 0.f, 0.f, 0.f};
#pragma unroll
      for (int t = 0; t < 4; t++) {
        int k0 = t * 32 + kg;
        const float* ap = X + grow + k0;
        float a8[8];
        *(f32x4*)(a8) = *(const f32x4*)ap;
        *(f32x4*)(a8 + 4) = *(const f32x4*)(ap + 4);
        short8 af;
#pragma unroll
        for (int i = 0; i < 8; i++) af[i] = (short)f2bf(a8[i]);
#pragma unroll
        for (int j = 0; j < 4; j++) {
          short8 bf = *(const short8*)&wt[(chh * 4 + j) * 16 + l15][k0];
          acc[j] = __builtin_amdgcn_mfma_f32_16x16x32_bf16(af, bf, acc[j], 0, 0, 0);
        }
      }
      int crow = rt * 16 + (lane >> 4) * 4;
#pragma unroll
      for (int rr = 0; rr < 4; rr++) {
        int row = crow + rr;
        int n = (bc * 64 + row) & (S - 1);
        float sc;
        if (mat == 0) {
          sc = expf(-lgf * (float)n) * 0.088388347f;          // gamma^-n/sqrt(128)
        } else if (mat == 1) {
          float rs = (expf(-lgf * (float)(n + 1)) - 1.f) * (GAMMA_F / (1.f - GAMMA_F));
          sc = expf(lgf * (float)n) / sqrtf(rs);              // gamma^n/sqrt(rowsum)
        } else {
          sc = 1.f;
        }
#pragma unroll
        for (int j = 0; j < 4; j++)
          qkv[mat][row][(chh * 4 + j) * 16 + l15] = f2bf(acc[j][rr] * sc);
      }
    }
  }
  // ---- P1b: csp partials = ysum @ wt (per-quarter) ----
  {
    int d = tid & 127, q = tid >> 7;
    float part = 0.f;
#pragma unroll
    for (int k = 0; k < 32; k++) part = fmaf(ysum[32 * q + k], bf2f(wt[d][32 * q + k]), part);
    cspp[q][d] = part;
  }
  __syncthreads();   // qkv, cspp ready; wt dead -> ovl becomes kT/vT

  // ---- P2: qb write | A-tile -> al,rsum | kT pack | vT raw pack | csp finalize ----
  if (tid < 128) csp[tid] = cspp[0][tid] + cspp[1][tid] + cspp[2][tid] + cspp[3][tid];
  {  // qb global write
    int row = tid >> 3, col = (tid & 7) * 16;
    unsigned short* dst = qb + (size_t)(bc * 64 + row) * 128 + col;
    *(ushort8*)dst = *(const ushort8*)&qkv[0][row][col];
    *(ushort8*)(dst + 8) = *(const ushort8*)&qkv[0][row][col + 8];
  }
  {  // A = tril(Q'K''^T): wave w: rt2=w&3 rows, mh=w>>2 col pair
    int rt2 = w & 3, mh = w >> 2;
    int arow = rt2 * 16 + l15;
    int crow = rt2 * 16 + (lane >> 4) * 4;
    f32x4 a1[2];
#pragma unroll
    for (int mi = 0; mi < 2; mi++) a1[mi] = (f32x4){0.f, 0.f, 0.f, 0.f};
#pragma unroll
    for (int t = 0; t < 4; t++) {
      int k0 = t * 32 + kg;
      short8 af = *(const short8*)&qkv[0][arow][k0];
#pragma unroll
      for (int mi = 0; mi < 2; mi++) {
        short8 bf = *(const short8*)&qkv[1][(mh * 2 + mi) * 16 + l15][k0];
        a1[mi] = __builtin_amdgcn_mfma_f32_16x16x32_bf16(af, bf, a1[mi], 0, 0, 0);
      }
    }
    unsigned short* alg = al + (size_t)bc * 64 * 64;
    float rsp[4] = {0.f, 0.f, 0.f, 0.f};
#pragma unroll
    for (int mi = 0; mi < 2; mi++)
#pragma unroll
      for (int rr = 0; rr < 4; rr++) {
        int n_l = crow + rr, m_l = (mh * 2 + mi) * 16 + l15;
        float mv = (n_l >= m_l) ? a1[mi][rr] : 0.f;
        alg[n_l * 64 + m_l] = f2bf(mv);
        rsp[rr] += mv;
      }
#pragma unroll
    for (int rr = 0; rr < 4; rr++) {
      float r = rsp[rr];
      r += __shfl_xor(r, 1); r += __shfl_xor(r, 2);
      r += __shfl_xor(r, 4); r += __shfl_xor(r, 8);
      if (l15 == 0) rsum_l[mh][crow + rr] = r;
    }
  }
  {  // kT pack (K''^T, m-fast)
    int d = tid & 127, mh2 = tid >> 7;
#pragma unroll
    for (int mg = 0; mg < 2; mg++) {
      ushort8 pk;
#pragma unroll
      for (int i = 0; i < 8; i++) pk[i] = qkv[1][mh2 * 16 + mg * 8 + i][d];
      *(ushort8*)&kT[d][mh2 * 16 + mg * 8] = pk;
    }
  }
  {  // vT raw pack (V^T, unscaled)
    int d = tid & 127, mh2 = tid >> 7;
#pragma unroll
    for (int mg = 0; mg < 2; mg++) {
      ushort8 pk;
#pragma unroll
      for (int i = 0; i < 8; i++) pk[i] = qkv[2][mh2 * 16 + mg * 8 + i][d];
      *(ushort8*)&vT[d][mh2 * 16 + mg * 8] = pk;
    }
  }
  __syncthreads();   // csp, rsum_l, kT, vT(raw) ready

  // ---- P3: s = rowsum(A) + Q'.csp ; invl ----
  {
    int row = tid >> 3, part = tid & 7;
    ushort8 q8a = *(const ushort8*)&qkv[0][row][part * 16];
    ushort8 q8b = *(const ushort8*)&qkv[0][row][part * 16 + 8];
    float dot = 0.f;
#pragma unroll
    for (int ii = 0; ii < 8; ii++) {
      dot = fmaf(bf2f(q8a[ii]), csp[part * 16 + ii], dot);
      dot = fmaf(bf2f(q8b[ii]), csp[part * 16 + 8 + ii], dot);
    }
    dot += __shfl_xor(dot, 1); dot += __shfl_xor(dot, 2); dot += __shfl_xor(dot, 4);
    if (part == 0) {
      float s = rsum_l[0][row] + rsum_l[1][row] + dot;
      invl[row] = 1.f / fmaxf(fabsf(s), 1.f);
    }
  }
  __syncthreads();   // invl ready

  // ---- P4: scale vT in place by invl[m] ----
  {
    int d = tid >> 2, ms = (tid & 3) * 16;
#pragma unroll
    for (int g = 0; g < 2; g++) {
      ushort8 v8 = *(const ushort8*)&vT[d][ms + g * 8];
      ushort8 o;
#pragma unroll
      for (int ii = 0; ii < 8; ii++) o[ii] = f2bf(bf2f(v8[ii]) * invl[ms + g * 8 + ii]);
      *(ushort8*)&vT[d][ms + g * 8] = o;
    }
  }
  __syncthreads();   // vT = V'^T ready

  // ---- P5: Hc = (K''^T V')^T via MFMA ; vbT global write ----
  {
    f32x4 hacc[8];
#pragma unroll
    for (int j = 0; j < 8; j++) hacc[j] = (f32x4){0.f, 0.f, 0.f, 0.f};
#pragma unroll
    for (int t = 0; t < 2; t++) {
      int k0 = t * 32 + kg;
      short8 a2 = *(const short8*)&vT[w * 16 + l15][k0];
#pragma unroll
      for (int j = 0; j < 8; j++) {
        short8 bf = *(const short8*)&kT[j * 16 + l15][k0];
        hacc[j] = __builtin_amdgcn_mfma_f32_16x16x32_bf16(a2, bf, hacc[j], 0, 0, 0);
      }
    }
    unsigned short* g = Hc + (size_t)bc * D * D;
#pragma unroll
    for (int j = 0; j < 8; j++)
#pragma unroll
      for (int rr = 0; rr < 4; rr++)
        g[(size_t)(w * 16 + (lane >> 4) * 4 + rr) * D + j * 16 + l15] =
            f2bf(hacc[j][rr]);
  }
  {
    int d = tid >> 2, pp = (tid & 3) * 16;
    unsigned short* dst = vbT + (size_t)bc * D * C + (size_t)d * C + pp;
    *(ushort8*)(dst) = *(const ushort8*)&vT[d][pp];
    *(ushort8*)(dst + 8) = *(const ushort8*)&vT[d][pp + 8];
  }
}

// ---------------- K2: HS = exclusive chunk prefix of Hc ----------------
__global__ __launch_bounds__(64) void k_gscan(const unsigned short* __restrict__ Hc,
                                              unsigned short* __restrict__ HS) {
  int b = blockIdx.x, gy = blockIdx.y, t = threadIdx.x;
  int d2 = gy * 4 + (t >> 4), d1 = (t & 15) * 8;
  size_t off = ((size_t)(b * NC) * D + d2) * D + d1;
  ushort8 v[NC];
#pragma unroll
  for (int c = 0; c < NC; c++)
    v[c] = *(const ushort8*)(Hc + off + (size_t)c * D * D);
  float run[8];
#pragma unroll
  for (int j = 0; j < 8; j++) run[j] = 0.f;
#pragma unroll
  for (int c = 0; c < NC; c++) {
    ushort8 o;
#pragma unroll
    for (int j = 0; j < 8; j++) {
      o[j] = f2bf(run[j]);
      run[j] += bf2f(v[c][j]);
    }
    *(ushort8*)(HS + off + (size_t)c * D * D) = o;
  }
}

// ---------------- K3: out = Q'@SE + A@V' (512 threads, no LDS) ----------------
__global__ __launch_bounds__(512) void k_out(
    const unsigned short* __restrict__ qb, const unsigned short* __restrict__ al,
    const unsigned short* __restrict__ vbT, const unsigned short* __restrict__ HS,
    float* __restrict__ out) {
  int bc = blockIdx.x, tid = threadIdx.x, w = tid >> 6, lane = tid & 63;
  int l15 = lane & 15;
  size_t base = (size_t)bc * C * D;
  int kg = (lane >> 4) * 8;
  int rt = w >> 1, ch = w & 1;
  int arow = rt * 16 + l15;
  int crow = rt * 16 + (lane >> 4) * 4;

  f32x4 acc[4];
#pragma unroll
  for (int j = 0; j < 4; j++) acc[j] = (f32x4){0.f, 0.f, 0.f, 0.f};
  const unsigned short* hrow = HS + (size_t)bc * D * D;
#pragma unroll
  for (int t = 0; t < 4; t++) {
    int k0 = t * 32 + kg;
    short8 af = *(const short8*)(qb + base + (size_t)arow * D + k0);
#pragma unroll
    for (int jj = 0; jj < 4; jj++) {
      int j = ch * 4 + jj;
      short8 bf = *(const short8*)(hrow + (size_t)(j * 16 + l15) * D + k0);
      acc[jj] = __builtin_amdgcn_mfma_f32_16x16x32_bf16(af, bf, acc[jj], 0, 0, 0);
    }
  }
  const unsigned short* alg = al + (size_t)bc * 64 * 64;
  const unsigned short* vt = vbT + (size_t)bc * D * C;
#pragma unroll
  for (int t = 0; t < 2; t++) {
    int k0 = t * 32 + kg;
    short8 af = *(const short8*)(alg + (size_t)arow * 64 + k0);
#pragma unroll
    for (int jj = 0; jj < 4; jj++) {
      int j = ch * 4 + jj;
      short8 bf = *(const short8*)(vt + (size_t)(j * 16 + l15) * C + k0);
      acc[jj] = __builtin_amdgcn_mfma_f32_16x16x32_bf16(af, bf, acc[jj], 0, 0, 0);
    }
  }
#pragma unroll
  for (int jj = 0; jj < 4; jj++)
#pragma unroll
    for (int rr = 0; rr < 4; rr++)
      out[base + (size_t)(crow + rr) * D + (ch * 4 + jj) * 16 + l15] = acc[jj][rr];
}

extern "C" void kernel_launch(void* const* d_in, const int* in_sizes, int n_in,
                              void* d_out, int out_size, void* d_ws, size_t ws_size,
                              hipStream_t stream) {
  const float* xq = (const float*)d_in[0];
  const float* xk = (const float*)d_in[1];
  const float* xv = (const float*)d_in[2];
  const float* W  = (const float*)d_in[3];
  float* out = (float*)d_out;

  char* p = (char*)d_ws;
  float* yc = (float*)p;                     p += (size_t)NCH * D * 4;
  unsigned short* qb  = (unsigned short*)p;  p += (size_t)BS * D * 2;
  unsigned short* al  = (unsigned short*)p;  p += (size_t)NCH * C * C * 2;
  unsigned short* vbT = (unsigned short*)p;  p += (size_t)NCH * D * C * 2;
  unsigned short* Hc  = (unsigned short*)p;  p += (size_t)NCH * D * D * 2;
  unsigned short* HS  = (unsigned short*)p;  p += (size_t)NCH * D * D * 2;

  hipLaunchKernelGGL(k_y, dim3(NCH), dim3(128), 0, stream, xk, yc);
  hipLaunchKernelGGL(k_big, dim3(NCH), dim3(512), 0, stream,
                     xq, xk, xv, W, yc, qb, al, vbT, Hc);
  hipLaunchKernelGGL(k_gscan, dim3(B, 32), dim3(64), 0, stream, Hc, HS);
  hipLaunchKernelGGL(k_out, dim3(NCH), dim3(512), 0, stream, qb, al, vbT, HS, out);
}